// Round 1
// baseline (270.262 us; speedup 1.0000x reference)
//
#include <hip/hip_runtime.h>
#include <hip/hip_bf16.h>
#include <stdint.h>

#define TSEQ 2048
#define DMODEL 1024
#define NHEAD 16
#define HDIM 64
#define NBATCH 2
#define BHN 32
#define MROWS 4096
#define L2E 1.44269504088896340736f

typedef unsigned short u16;
typedef __attribute__((ext_vector_type(8))) short bf16x8;
typedef __attribute__((ext_vector_type(8))) unsigned short u16x8;
typedef __attribute__((ext_vector_type(4))) unsigned short u16x4;
typedef __attribute__((ext_vector_type(4))) float f32x4;

__device__ inline u16 f2bf(float f) {
  __hip_bfloat16 h(f);
  return __builtin_bit_cast(u16, h);
}

__device__ inline void gload16(const void* g, void* l) {
  __builtin_amdgcn_global_load_lds((const __attribute__((address_space(1))) void*)g,
                                   (__attribute__((address_space(3))) void*)l, 16, 0, 0);
}

// ---------------- f32 -> bf16 elementwise ----------------
__global__ void cvt_bf16(const float* __restrict__ in, u16* __restrict__ out, int n) {
  int i = (blockIdx.x * blockDim.x + threadIdx.x) * 4;
  if (i + 3 < n) {
    float4 v = *(const float4*)(in + i);
    u16x4 o;
    o.x = f2bf(v.x); o.y = f2bf(v.y); o.z = f2bf(v.z); o.w = f2bf(v.w);
    *(u16x4*)(out + i) = o;
  }
}

// ---------------- weight transpose: W[1024][1024] f32 -> WT[n][k] bf16 ----------------
__global__ void wtrans(const float* __restrict__ W, u16* __restrict__ WT) {
  __shared__ float tile[32][33];
  const int bx = blockIdx.x, by = blockIdx.y;
  const int tr = threadIdx.x >> 3;        // 0..31
  const int tc4 = (threadIdx.x & 7) * 4;  // 0..28
  float4 v = *(const float4*)(W + (size_t)(by * 32 + tr) * 1024 + bx * 32 + tc4);
  tile[tr][tc4 + 0] = v.x; tile[tr][tc4 + 1] = v.y;
  tile[tr][tc4 + 2] = v.z; tile[tr][tc4 + 3] = v.w;
  __syncthreads();
  u16x4 o;
  o.x = f2bf(tile[tc4 + 0][tr]); o.y = f2bf(tile[tc4 + 1][tr]);
  o.z = f2bf(tile[tc4 + 2][tr]); o.w = f2bf(tile[tc4 + 3][tr]);
  *(u16x4*)(WT + (size_t)(bx * 32 + tr) * 1024 + by * 32 + tc4) = o;
}

// ---------------- mask tile flags: 1 if 128x128 tile is all ones ----------------
__global__ void maskflag(const int* __restrict__ mask, int* __restrict__ flags) {
  const int st = blockIdx.x, qt = blockIdx.y, b = blockIdx.z;
  const int row = qt * 128 + (threadIdx.x >> 1);
  const int col0 = st * 128 + (threadIdx.x & 1) * 64;
  const int* p = mask + (size_t)b * TSEQ * TSEQ + (size_t)row * TSEQ + col0;
  int ok = 1;
  #pragma unroll
  for (int j = 0; j < 64; j += 4) {
    int4 v = *(const int4*)(p + j);
    ok &= (v.x == 1) & (v.y == 1) & (v.z == 1) & (v.w == 1);
  }
  ok = __all(ok);
  __shared__ int s[4];
  if ((threadIdx.x & 63) == 0) s[threadIdx.x >> 6] = ok;
  __syncthreads();
  if (threadIdx.x == 0) flags[(b * 16 + qt) * 16 + st] = s[0] & s[1] & s[2] & s[3];
}

// ---------------- V[bh][t][64] -> VT[bh][64][t] (bf16) ----------------
__global__ void vtrans(const u16* __restrict__ V, u16* __restrict__ VT) {
  __shared__ u16 tile[64][72];
  const int bh = blockIdx.y;
  const int t0 = blockIdx.x * 64;
  const u16* src = V + ((size_t)bh * TSEQ + t0) * 64;
  const int r = threadIdx.x >> 3, sg = threadIdx.x & 7;
  #pragma unroll
  for (int i = 0; i < 2; ++i) {
    int row = r + i * 32;
    u16x8 v = *(const u16x8*)(src + (size_t)row * 64 + sg * 8);
    #pragma unroll
    for (int j = 0; j < 8; ++j) tile[row][sg * 8 + j] = v[j];
  }
  __syncthreads();
  u16* dst = VT + (size_t)bh * 64 * TSEQ;
  #pragma unroll
  for (int i = 0; i < 2; ++i) {
    int v = r + i * 32;
    u16x8 o;
    #pragma unroll
    for (int j = 0; j < 8; ++j) o[j] = tile[sg * 8 + j][v];
    *(u16x8*)(dst + (size_t)v * TSEQ + t0 + sg * 8) = o;
  }
}

// ---------------- GEMM: A[4096][1024] bf16 x BT[1024][1024] bf16 ----------------
// mode 0: out bf16 scattered to [B,H,T,64], val=(acc+bias)*scale
// mode 1: out f32 row-major [4096][1024], val=acc+bias
__global__ void gemm_bt(const u16* __restrict__ A, const u16* __restrict__ BT,
                        const float* __restrict__ bias, void* __restrict__ Cout,
                        int mode, float scale) {
  __shared__ u16 As[128 * 64];
  __shared__ u16 Bs[128 * 64];
  const int tid = threadIdx.x;
  const int w = tid >> 6, lane = tid & 63;
  const int lo = lane & 15, hi = lane >> 4;
  const int m0 = blockIdx.x * 128, n0 = blockIdx.y * 128;
  const int wm = (w >> 1) * 64, wn = (w & 1) * 64;
  f32x4 acc[4][4] = {};
  const int loff = w * 4096 + lane * 16;
  for (int kt = 0; kt < 16; ++kt) {
    #pragma unroll
    for (int i = 0; i < 4; ++i) {
      const int off = loff + i * 1024;     // byte offset in tile
      const int row = off >> 7;            // 128B rows
      const int segp = (off >> 4) & 7;
      const int g = segp ^ (row & 7);      // pre-swizzled global segment
      gload16(A + (size_t)(m0 + row) * 1024 + kt * 64 + g * 8, (char*)As + off);
      gload16(BT + (size_t)(n0 + row) * 1024 + kt * 64 + g * 8, (char*)Bs + off);
    }
    __syncthreads();
    #pragma unroll
    for (int kk = 0; kk < 2; ++kk) {
      bf16x8 af[4], bfr[4];
      #pragma unroll
      for (int mi = 0; mi < 4; ++mi) {
        int row = wm + mi * 16 + lo;
        int p = (kk * 4 + hi) ^ (row & 7);
        af[mi] = *(const bf16x8*)(As + row * 64 + p * 8);
      }
      #pragma unroll
      for (int ni = 0; ni < 4; ++ni) {
        int row = wn + ni * 16 + lo;
        int p = (kk * 4 + hi) ^ (row & 7);
        bfr[ni] = *(const bf16x8*)(Bs + row * 64 + p * 8);
      }
      #pragma unroll
      for (int mi = 0; mi < 4; ++mi)
        #pragma unroll
        for (int ni = 0; ni < 4; ++ni)
          acc[mi][ni] = __builtin_amdgcn_mfma_f32_16x16x32_bf16(af[mi], bfr[ni], acc[mi][ni], 0, 0, 0);
    }
    __syncthreads();
  }
  #pragma unroll
  for (int ni = 0; ni < 4; ++ni) {
    const int col = n0 + wn + ni * 16 + lo;
    const float bc = bias[col];
    #pragma unroll
    for (int mi = 0; mi < 4; ++mi) {
      #pragma unroll
      for (int r = 0; r < 4; ++r) {
        const int row = m0 + wm + mi * 16 + hi * 4 + r;
        const float v = (acc[mi][ni][r] + bc) * scale;
        if (mode == 0) {
          ((u16*)Cout)[(size_t)(((row >> 11) * NHEAD + (col >> 6)) * TSEQ + (row & 2047)) * HDIM + (col & 63)] = f2bf(v);
        } else {
          ((float*)Cout)[(size_t)row * DMODEL + col] = v;
        }
      }
    }
  }
}

// ---------------- flash attention ----------------
// Q[bh][t][64] (pre-scaled by 1/8), K[bh][t][64], VT[bh][64][t]; ctx[b*T+t][h*64+v] bf16
__global__ __launch_bounds__(256) void flash(
    const u16* __restrict__ Q, const u16* __restrict__ K, const u16* __restrict__ VT,
    const int* __restrict__ mask, const int* __restrict__ flags, u16* __restrict__ ctx) {
  __shared__ u16 Ks[128 * 64];     // [s][dk], seg^=(s&7)
  __shared__ u16 Vs[64 * 128];     // [v][s], seg^=(v&15)
  __shared__ u16 Ps[4][32 * 128];  // per wave [t][s], seg^=(t&7)
  const int tid = threadIdx.x, w = tid >> 6, lane = tid & 63;
  const int lo = lane & 15, hi = lane >> 4;
  const int qt = blockIdx.x, bh = blockIdx.y;
  const int b = bh >> 4, h = bh & 15;
  const int q0 = qt * 128;
  u16* Pw = &Ps[w][0];

  // Q fragments in registers
  bf16x8 qf[2][2];
  #pragma unroll
  for (int mi = 0; mi < 2; ++mi)
    #pragma unroll
    for (int kk = 0; kk < 2; ++kk) {
      int t = q0 + w * 32 + mi * 16 + lo;
      qf[mi][kk] = *(const bf16x8*)(Q + ((size_t)bh * TSEQ + t) * 64 + kk * 32 + hi * 8);
    }

  f32x4 o[2][4] = {};
  float mrow[2][4], lrow[2][4];
  #pragma unroll
  for (int mi = 0; mi < 2; ++mi)
    #pragma unroll
    for (int r = 0; r < 4; ++r) { mrow[mi][r] = -1e30f; lrow[mi][r] = 0.f; }

  for (int st = 0; st < 16; ++st) {
    #pragma unroll
    for (int i = 0; i < 4; ++i) {
      const int off = w * 4096 + i * 1024 + lane * 16;
      { // K tile: rows 128B
        int s = off >> 7, segp = (off >> 4) & 7, g = segp ^ (s & 7);
        gload16(K + ((size_t)bh * TSEQ + st * 128 + s) * 64 + g * 8, (char*)Ks + off);
      }
      { // VT tile: rows 256B
        int v = off >> 8, segp = (off >> 4) & 15, g = segp ^ (v & 15);
        gload16(VT + ((size_t)bh * 64 + v) * TSEQ + st * 128 + g * 8, (char*)Vs + off);
      }
    }
    __syncthreads();
    const int allones = flags[(b * 16 + qt) * 16 + st];

    // S = Q K^T  (rows t, cols s)
    f32x4 sc[2][8] = {};
    #pragma unroll
    for (int kk = 0; kk < 2; ++kk) {
      #pragma unroll
      for (int ni = 0; ni < 8; ++ni) {
        int srow = ni * 16 + lo;
        int p = (kk * 4 + hi) ^ (srow & 7);
        bf16x8 kf = *(const bf16x8*)(Ks + srow * 64 + p * 8);
        #pragma unroll
        for (int mi = 0; mi < 2; ++mi)
          sc[mi][ni] = __builtin_amdgcn_mfma_f32_16x16x32_bf16(qf[mi][kk], kf, sc[mi][ni], 0, 0, 0);
      }
    }

    if (!allones) {
      #pragma unroll
      for (int mi = 0; mi < 2; ++mi)
        #pragma unroll
        for (int ni = 0; ni < 8; ++ni)
          #pragma unroll
          for (int r = 0; r < 4; ++r) {
            int t = q0 + w * 32 + mi * 16 + hi * 4 + r;
            int s = st * 128 + ni * 16 + lo;
            int mv = mask[(size_t)b * TSEQ * TSEQ + (size_t)t * TSEQ + s];
            sc[mi][ni][r] += (1.0f - (float)mv) * -10000.0f;
          }
    }

    // online softmax per row
    #pragma unroll
    for (int mi = 0; mi < 2; ++mi) {
      #pragma unroll
      for (int r = 0; r < 4; ++r) {
        float pm = sc[mi][0][r];
        #pragma unroll
        for (int ni = 1; ni < 8; ++ni) pm = fmaxf(pm, sc[mi][ni][r]);
        pm = fmaxf(pm, __shfl_xor(pm, 1));
        pm = fmaxf(pm, __shfl_xor(pm, 2));
        pm = fmaxf(pm, __shfl_xor(pm, 4));
        pm = fmaxf(pm, __shfl_xor(pm, 8));
        float mold = mrow[mi][r];
        float mnew = fmaxf(mold, pm);
        float alpha = exp2f((mold - mnew) * L2E);
        mrow[mi][r] = mnew;
        float rs = 0.f;
        #pragma unroll
        for (int ni = 0; ni < 8; ++ni) {
          float p = exp2f((sc[mi][ni][r] - mnew) * L2E);
          sc[mi][ni][r] = p;
          rs += p;
        }
        rs += __shfl_xor(rs, 1); rs += __shfl_xor(rs, 2);
        rs += __shfl_xor(rs, 4); rs += __shfl_xor(rs, 8);
        lrow[mi][r] = lrow[mi][r] * alpha + rs;
        #pragma unroll
        for (int nj = 0; nj < 4; ++nj) o[mi][nj][r] *= alpha;
      }
    }

    // write P (bf16) to wave-private LDS, swizzled
    #pragma unroll
    for (int mi = 0; mi < 2; ++mi)
      #pragma unroll
      for (int ni = 0; ni < 8; ++ni)
        #pragma unroll
        for (int r = 0; r < 4; ++r) {
          int tl = mi * 16 + hi * 4 + r;
          int s = ni * 16 + lo;
          Pw[tl * 128 + (((s >> 3) ^ (tl & 7)) << 3) + (s & 7)] = f2bf(sc[mi][ni][r]);
        }

    // O += P V
    #pragma unroll
    for (int kk = 0; kk < 4; ++kk) {
      bf16x8 pa[2];
      #pragma unroll
      for (int mi = 0; mi < 2; ++mi) {
        int tl = mi * 16 + lo;
        int p = (kk * 4 + hi) ^ (tl & 7);
        pa[mi] = *(const bf16x8*)(Pw + tl * 128 + p * 8);
      }
      #pragma unroll
      for (int nj = 0; nj < 4; ++nj) {
        int v = nj * 16 + lo;
        int p = (kk * 4 + hi) ^ (v & 15);
        bf16x8 vf = *(const bf16x8*)(Vs + v * 128 + p * 8);
        #pragma unroll
        for (int mi = 0; mi < 2; ++mi)
          o[mi][nj] = __builtin_amdgcn_mfma_f32_16x16x32_bf16(pa[mi], vf, o[mi][nj], 0, 0, 0);
      }
    }
    __syncthreads();
  }

  // epilogue: normalize and store ctx
  #pragma unroll
  for (int mi = 0; mi < 2; ++mi) {
    float inv[4];
    #pragma unroll
    for (int r = 0; r < 4; ++r) inv[r] = 1.0f / lrow[mi][r];
    #pragma unroll
    for (int nj = 0; nj < 4; ++nj)
      #pragma unroll
      for (int r = 0; r < 4; ++r) {
        int t = q0 + w * 32 + mi * 16 + hi * 4 + r;
        int col = h * 64 + nj * 16 + lo;
        ctx[(size_t)(b * TSEQ + t) * DMODEL + col] = f2bf(o[mi][nj][r] * inv[r]);
      }
  }
}

extern "C" void kernel_launch(void* const* d_in, const int* in_sizes, int n_in,
                              void* d_out, int out_size, void* d_ws, size_t ws_size,
                              hipStream_t stream) {
  (void)in_sizes; (void)n_in; (void)out_size; (void)ws_size;
  const float* query = (const float*)d_in[0];
  const float* value = (const float*)d_in[1];
  const float* Wq = (const float*)d_in[2];
  const float* bq = (const float*)d_in[3];
  const float* Wk = (const float*)d_in[4];
  const float* bk = (const float*)d_in[5];
  const float* Wv = (const float*)d_in[6];
  const float* bv = (const float*)d_in[7];
  const float* Wo = (const float*)d_in[8];
  const float* bo = (const float*)d_in[9];
  const int* amask = (const int*)d_in[10];

  char* ws = (char*)d_ws;
  const size_t MB = 1 << 20;
  u16* qxb = (u16*)(ws + 0 * MB);
  u16* vxb = (u16*)(ws + 8 * MB);
  u16* WqT = (u16*)(ws + 16 * MB);
  u16* WkT = (u16*)(ws + 18 * MB);
  u16* WvT = (u16*)(ws + 20 * MB);
  u16* WoT = (u16*)(ws + 22 * MB);
  u16* Qb  = (u16*)(ws + 24 * MB);
  u16* Kb  = (u16*)(ws + 32 * MB);
  u16* Vb  = (u16*)(ws + 40 * MB);
  u16* VTb = (u16*)(ws + 48 * MB);
  u16* ctx = (u16*)(ws + 56 * MB);
  int* flg = (int*)(ws + 64 * MB);

  cvt_bf16<<<4096, 256, 0, stream>>>(query, qxb, MROWS * DMODEL);
  cvt_bf16<<<4096, 256, 0, stream>>>(value, vxb, MROWS * DMODEL);
  wtrans<<<dim3(32, 32), 256, 0, stream>>>(Wq, WqT);
  wtrans<<<dim3(32, 32), 256, 0, stream>>>(Wk, WkT);
  wtrans<<<dim3(32, 32), 256, 0, stream>>>(Wv, WvT);
  wtrans<<<dim3(32, 32), 256, 0, stream>>>(Wo, WoT);
  maskflag<<<dim3(16, 16, 2), 256, 0, stream>>>(amask, flg);

  gemm_bt<<<dim3(32, 8), 256, 0, stream>>>(qxb, WqT, bq, Qb, 0, 0.125f);
  gemm_bt<<<dim3(32, 8), 256, 0, stream>>>(vxb, WkT, bk, Kb, 0, 1.0f);
  gemm_bt<<<dim3(32, 8), 256, 0, stream>>>(vxb, WvT, bv, Vb, 0, 1.0f);
  vtrans<<<dim3(32, 32), 256, 0, stream>>>(Vb, VTb);
  flash<<<dim3(16, 32), 256, 0, stream>>>(Qb, Kb, VTb, amask, flg, ctx);
  gemm_bt<<<dim3(32, 8), 256, 0, stream>>>(ctx, WoT, bo, d_out, 1, 1.0f);
}

// Round 2
// 212.069 us; speedup vs baseline: 1.2744x; 1.2744x over previous
//
#include <hip/hip_runtime.h>
#include <hip/hip_bf16.h>
#include <stdint.h>

#define TSEQ 2048
#define DMODEL 1024
#define NHEAD 16
#define HDIM 64
#define NBATCH 2
#define BHN 32
#define MROWS 4096
#define L2E 1.44269504088896340736f

typedef unsigned short u16;
typedef __attribute__((ext_vector_type(8))) short bf16x8;
typedef __attribute__((ext_vector_type(8))) unsigned short u16x8;
typedef __attribute__((ext_vector_type(4))) unsigned short u16x4;
typedef __attribute__((ext_vector_type(4))) float f32x4;

__device__ inline u16 f2bf(float f) {
  __hip_bfloat16 h(f);
  return __builtin_bit_cast(u16, h);
}

__device__ inline void gload16(const void* g, void* l) {
  __builtin_amdgcn_global_load_lds((const __attribute__((address_space(1))) void*)g,
                                   (__attribute__((address_space(3))) void*)l, 16, 0, 0);
}

// ---------------- f32 -> bf16 elementwise ----------------
__global__ void cvt_bf16(const float* __restrict__ in, u16* __restrict__ out, int n) {
  int i = (blockIdx.x * blockDim.x + threadIdx.x) * 4;
  if (i + 3 < n) {
    float4 v = *(const float4*)(in + i);
    u16x4 o;
    o.x = f2bf(v.x); o.y = f2bf(v.y); o.z = f2bf(v.z); o.w = f2bf(v.w);
    *(u16x4*)(out + i) = o;
  }
}

// ---------------- weight transpose: W[1024][1024] f32 -> WT[n][k] bf16 ----------------
__global__ void wtrans(const float* __restrict__ W, u16* __restrict__ WT) {
  __shared__ float tile[32][33];
  const int bx = blockIdx.x, by = blockIdx.y;
  const int tr = threadIdx.x >> 3;        // 0..31
  const int tc4 = (threadIdx.x & 7) * 4;  // 0..28
  float4 v = *(const float4*)(W + (size_t)(by * 32 + tr) * 1024 + bx * 32 + tc4);
  tile[tr][tc4 + 0] = v.x; tile[tr][tc4 + 1] = v.y;
  tile[tr][tc4 + 2] = v.z; tile[tr][tc4 + 3] = v.w;
  __syncthreads();
  u16x4 o;
  o.x = f2bf(tile[tc4 + 0][tr]); o.y = f2bf(tile[tc4 + 1][tr]);
  o.z = f2bf(tile[tc4 + 2][tr]); o.w = f2bf(tile[tc4 + 3][tr]);
  *(u16x4*)(WT + (size_t)(bx * 32 + tr) * 1024 + by * 32 + tc4) = o;
}

// ---------------- mask tile flags: 1 if 128x128 tile is all ones ----------------
__global__ void maskflag(const int* __restrict__ mask, int* __restrict__ flags) {
  const int st = blockIdx.x, qt = blockIdx.y, b = blockIdx.z;
  const int row = qt * 128 + (threadIdx.x >> 1);
  const int col0 = st * 128 + (threadIdx.x & 1) * 64;
  const int* p = mask + (size_t)b * TSEQ * TSEQ + (size_t)row * TSEQ + col0;
  int ok = 1;
  #pragma unroll
  for (int j = 0; j < 64; j += 4) {
    int4 v = *(const int4*)(p + j);
    ok &= (v.x == 1) & (v.y == 1) & (v.z == 1) & (v.w == 1);
  }
  ok = __all(ok);
  __shared__ int s[4];
  if ((threadIdx.x & 63) == 0) s[threadIdx.x >> 6] = ok;
  __syncthreads();
  if (threadIdx.x == 0) flags[(b * 16 + qt) * 16 + st] = s[0] & s[1] & s[2] & s[3];
}

// ---------------- V[bh][t][64] -> VT[bh][64][t] (bf16) ----------------
__global__ void vtrans(const u16* __restrict__ V, u16* __restrict__ VT) {
  __shared__ u16 tile[64][72];
  const int bh = blockIdx.y;
  const int t0 = blockIdx.x * 64;
  const u16* src = V + ((size_t)bh * TSEQ + t0) * 64;
  const int r = threadIdx.x >> 3, sg = threadIdx.x & 7;
  #pragma unroll
  for (int i = 0; i < 2; ++i) {
    int row = r + i * 32;
    u16x8 v = *(const u16x8*)(src + (size_t)row * 64 + sg * 8);
    #pragma unroll
    for (int j = 0; j < 8; ++j) tile[row][sg * 8 + j] = v[j];
  }
  __syncthreads();
  u16* dst = VT + (size_t)bh * 64 * TSEQ;
  #pragma unroll
  for (int i = 0; i < 2; ++i) {
    int v = r + i * 32;
    u16x8 o;
    #pragma unroll
    for (int j = 0; j < 8; ++j) o[j] = tile[sg * 8 + j][v];
    *(u16x8*)(dst + (size_t)v * TSEQ + t0 + sg * 8) = o;
  }
}

// ---------------- GEMM: A[4096][1024] bf16 x BT[1024][1024] bf16 ----------------
__global__ void gemm_bt(const u16* __restrict__ A, const u16* __restrict__ BT,
                        const float* __restrict__ bias, void* __restrict__ Cout,
                        int mode, float scale) {
  __shared__ u16 As[128 * 64];
  __shared__ u16 Bs[128 * 64];
  const int tid = threadIdx.x;
  const int w = tid >> 6, lane = tid & 63;
  const int lo = lane & 15, hi = lane >> 4;
  const int m0 = blockIdx.x * 128, n0 = blockIdx.y * 128;
  const int wm = (w >> 1) * 64, wn = (w & 1) * 64;
  f32x4 acc[4][4] = {};
  const int loff = w * 4096 + lane * 16;
  for (int kt = 0; kt < 16; ++kt) {
    #pragma unroll
    for (int i = 0; i < 4; ++i) {
      const int off = loff + i * 1024;
      const int row = off >> 7;
      const int segp = (off >> 4) & 7;
      const int g = segp ^ (row & 7);
      gload16(A + (size_t)(m0 + row) * 1024 + kt * 64 + g * 8, (char*)As + off);
      gload16(BT + (size_t)(n0 + row) * 1024 + kt * 64 + g * 8, (char*)Bs + off);
    }
    __syncthreads();
    #pragma unroll
    for (int kk = 0; kk < 2; ++kk) {
      bf16x8 af[4], bfr[4];
      #pragma unroll
      for (int mi = 0; mi < 4; ++mi) {
        int row = wm + mi * 16 + lo;
        int p = (kk * 4 + hi) ^ (row & 7);
        af[mi] = *(const bf16x8*)(As + row * 64 + p * 8);
      }
      #pragma unroll
      for (int ni = 0; ni < 4; ++ni) {
        int row = wn + ni * 16 + lo;
        int p = (kk * 4 + hi) ^ (row & 7);
        bfr[ni] = *(const bf16x8*)(Bs + row * 64 + p * 8);
      }
      #pragma unroll
      for (int mi = 0; mi < 4; ++mi)
        #pragma unroll
        for (int ni = 0; ni < 4; ++ni)
          acc[mi][ni] = __builtin_amdgcn_mfma_f32_16x16x32_bf16(af[mi], bfr[ni], acc[mi][ni], 0, 0, 0);
    }
    __syncthreads();
  }
  #pragma unroll
  for (int ni = 0; ni < 4; ++ni) {
    const int col = n0 + wn + ni * 16 + lo;
    const float bc = bias[col];
    #pragma unroll
    for (int mi = 0; mi < 4; ++mi) {
      #pragma unroll
      for (int r = 0; r < 4; ++r) {
        const int row = m0 + wm + mi * 16 + hi * 4 + r;
        const float v = (acc[mi][ni][r] + bc) * scale;
        if (mode == 0) {
          ((u16*)Cout)[(size_t)(((row >> 11) * NHEAD + (col >> 6)) * TSEQ + (row & 2047)) * HDIM + (col & 63)] = f2bf(v);
        } else {
          ((float*)Cout)[(size_t)row * DMODEL + col] = v;
        }
      }
    }
  }
}

// ---------------- flash attention (swapped-QK, defer-max, 2-phase dbuf) ----------------
// Q[bh][t][64] pre-scaled by 0.125*log2(e) so scores are in log2 units.
// K[bh][t][64], VT[bh][64][t]; ctx[b*T+t][h*64+v] bf16.
// Block: 4 waves x 16 q-rows (QBLK=64), KV tiles of 64. LDS 40KB -> 4 blocks/CU.
__global__ __launch_bounds__(256) void flash(
    const u16* __restrict__ Q, const u16* __restrict__ K, const u16* __restrict__ VT,
    const int* __restrict__ mask, const int* __restrict__ flags, u16* __restrict__ ctx) {
  __shared__ u16 Ks[2][64 * 64];
  __shared__ u16 Vs[2][64 * 64];
  __shared__ u16 Ps[4][16 * 64];
  const int tid = threadIdx.x, w = tid >> 6, lane = tid & 63;
  const int lo = lane & 15, hi = lane >> 4;
  const int qt = blockIdx.x, bh = blockIdx.y;
  const int b = bh >> 4, h = bh & 15;
  const int q0 = qt * 64;
  u16* Pw = &Ps[w][0];

  // staging geometry: per wave 2KB per tile-half; rows of 128B, swizzled source seg
  const int soff = w * 2048 + lane * 16;            // LDS byte offset (i*1024 added)
  const int srow0 = w * 16 + (lane >> 3);           // tile row for i=0 (+8 for i=1)
  const int g8 = (((lane & 7) ^ (lane >> 3)) << 3); // pre-swizzled global seg (u16 units)

  // Q fragments (B-operand): t = q0 + w*16 + lo, k = kk*32 + hi*8
  bf16x8 qf[2];
  #pragma unroll
  for (int kk = 0; kk < 2; ++kk)
    qf[kk] = *(const bf16x8*)(Q + ((size_t)bh * TSEQ + q0 + w * 16 + lo) * 64 + kk * 32 + hi * 8);

  f32x4 o[4] = {};
  float mrow = -1e30f, lrow = 0.f;

#define STAGE(buf, st_) do {                                                         \
    const u16* kb_ = K + ((size_t)bh * TSEQ + (st_) * 64) * 64;                      \
    const u16* vb_ = VT + (size_t)bh * 64 * TSEQ + (st_) * 64;                       \
    gload16(kb_ + (size_t)srow0 * 64 + g8, (char*)Ks[buf] + soff);                   \
    gload16(kb_ + (size_t)(srow0 + 8) * 64 + g8, (char*)Ks[buf] + soff + 1024);      \
    gload16(vb_ + (size_t)srow0 * TSEQ + g8, (char*)Vs[buf] + soff);                 \
    gload16(vb_ + (size_t)(srow0 + 8) * TSEQ + g8, (char*)Vs[buf] + soff + 1024);    \
  } while (0)

  int cur = 0;
  STAGE(0, 0);
  __syncthreads();

  for (int st = 0; st < 32; ++st) {
    if (st < 31) STAGE(cur ^ 1, st + 1);
    const u16* Ksb = Ks[cur];
    const u16* Vsb = Vs[cur];

    // S^T = K Q^T : lane holds S[t = q0+w*16+lo][s = st*64 + si*16 + hi*4 + r]
    f32x4 sc[4] = {};
    __builtin_amdgcn_s_setprio(1);
    #pragma unroll
    for (int kk = 0; kk < 2; ++kk) {
      const int p = ((kk * 4 + hi) ^ (lo & 7)) << 3;
      #pragma unroll
      for (int si = 0; si < 4; ++si) {
        bf16x8 kf = *(const bf16x8*)(Ksb + (si * 16 + lo) * 64 + p);
        sc[si] = __builtin_amdgcn_mfma_f32_16x16x32_bf16(kf, qf[kk], sc[si], 0, 0, 0);
      }
    }
    __builtin_amdgcn_s_setprio(0);

    if (!flags[(b * 16 + (qt >> 1)) * 16 + (st >> 1)]) {
      const int t = q0 + w * 16 + lo;
      #pragma unroll
      for (int si = 0; si < 4; ++si)
        #pragma unroll
        for (int r = 0; r < 4; ++r) {
          int s = st * 64 + si * 16 + hi * 4 + r;
          int mv = mask[(size_t)b * TSEQ * TSEQ + (size_t)t * TSEQ + s];
          sc[si][r] += (1.0f - (float)mv) * -14426.950408f;  // -10000 * log2(e)
        }
    }

    // row max (lane-local 16 values + 2 shfl across the 4 hi-copies)
    float pm = sc[0][0];
    #pragma unroll
    for (int si = 0; si < 4; ++si)
      #pragma unroll
      for (int r = 0; r < 4; ++r) pm = fmaxf(pm, sc[si][r]);
    pm = fmaxf(pm, __shfl_xor(pm, 16));
    pm = fmaxf(pm, __shfl_xor(pm, 32));

    // defer-max: only rescale when the running max grew by > 11 (log2 units)
    if (__any(pm - mrow > 11.0f)) {
      float mn = fmaxf(mrow, pm);
      float a = exp2f(mrow - mn);
      lrow *= a;
      mrow = mn;
      #pragma unroll
      for (int r = 0; r < 4; ++r) {
        float ar = __shfl(a, hi * 4 + r);
        #pragma unroll
        for (int vj = 0; vj < 4; ++vj) o[vj][r] *= ar;
      }
    }

    // P = exp2(S - m), row sum, pack to LDS (one b64 per si)
    float rs = 0.f;
    #pragma unroll
    for (int si = 0; si < 4; ++si) {
      u16x4 pk;
      #pragma unroll
      for (int r = 0; r < 4; ++r) {
        float p = exp2f(sc[si][r] - mrow);
        rs += p;
        pk[r] = f2bf(p);
      }
      const int seg = si * 2 + (hi >> 1);
      *(u16x4*)(Pw + lo * 64 + ((seg ^ (lo & 7)) << 3) + ((hi & 1) << 2)) = pk;
    }
    rs += __shfl_xor(rs, 16);
    rs += __shfl_xor(rs, 32);
    lrow += rs;

    // O += P V : A = P[t=lo][s], B = V[v=vj*16+lo][s]
    __builtin_amdgcn_s_setprio(1);
    #pragma unroll
    for (int kk = 0; kk < 2; ++kk) {
      const int p = ((kk * 4 + hi) ^ (lo & 7)) << 3;
      bf16x8 pa = *(const bf16x8*)(Pw + lo * 64 + p);
      #pragma unroll
      for (int vj = 0; vj < 4; ++vj) {
        bf16x8 vf = *(const bf16x8*)(Vsb + (vj * 16 + lo) * 64 + p);
        o[vj] = __builtin_amdgcn_mfma_f32_16x16x32_bf16(pa, vf, o[vj], 0, 0, 0);
      }
    }
    __builtin_amdgcn_s_setprio(0);

    __syncthreads();
    cur ^= 1;
  }
#undef STAGE

  // epilogue: normalize (redistribute 1/l to O-row lanes) and store ctx
  const float inv = 1.0f / lrow;
  #pragma unroll
  for (int r = 0; r < 4; ++r) {
    const float ir = __shfl(inv, hi * 4 + r);
    const int t = q0 + w * 16 + hi * 4 + r;
    #pragma unroll
    for (int vj = 0; vj < 4; ++vj) {
      const int col = h * 64 + vj * 16 + lo;
      ctx[(size_t)(b * TSEQ + t) * DMODEL + col] = f2bf(o[vj][r] * ir);
    }
  }
}

extern "C" void kernel_launch(void* const* d_in, const int* in_sizes, int n_in,
                              void* d_out, int out_size, void* d_ws, size_t ws_size,
                              hipStream_t stream) {
  (void)in_sizes; (void)n_in; (void)out_size; (void)ws_size;
  const float* query = (const float*)d_in[0];
  const float* value = (const float*)d_in[1];
  const float* Wq = (const float*)d_in[2];
  const float* bq = (const float*)d_in[3];
  const float* Wk = (const float*)d_in[4];
  const float* bk = (const float*)d_in[5];
  const float* Wv = (const float*)d_in[6];
  const float* bv = (const float*)d_in[7];
  const float* Wo = (const float*)d_in[8];
  const float* bo = (const float*)d_in[9];
  const int* amask = (const int*)d_in[10];

  char* ws = (char*)d_ws;
  const size_t MB = 1 << 20;
  u16* qxb = (u16*)(ws + 0 * MB);
  u16* vxb = (u16*)(ws + 8 * MB);
  u16* WqT = (u16*)(ws + 16 * MB);
  u16* WkT = (u16*)(ws + 18 * MB);
  u16* WvT = (u16*)(ws + 20 * MB);
  u16* WoT = (u16*)(ws + 22 * MB);
  u16* Qb  = (u16*)(ws + 24 * MB);
  u16* Kb  = (u16*)(ws + 32 * MB);
  u16* Vb  = (u16*)(ws + 40 * MB);
  u16* VTb = (u16*)(ws + 48 * MB);
  u16* ctx = (u16*)(ws + 56 * MB);
  int* flg = (int*)(ws + 64 * MB);

  cvt_bf16<<<4096, 256, 0, stream>>>(query, qxb, MROWS * DMODEL);
  cvt_bf16<<<4096, 256, 0, stream>>>(value, vxb, MROWS * DMODEL);
  wtrans<<<dim3(32, 32), 256, 0, stream>>>(Wq, WqT);
  wtrans<<<dim3(32, 32), 256, 0, stream>>>(Wk, WkT);
  wtrans<<<dim3(32, 32), 256, 0, stream>>>(Wv, WvT);
  wtrans<<<dim3(32, 32), 256, 0, stream>>>(Wo, WoT);
  maskflag<<<dim3(16, 16, 2), 256, 0, stream>>>(amask, flg);

  // Q pre-scaled by 0.125 * log2(e) so attention scores are in log2 units.
  gemm_bt<<<dim3(32, 8), 256, 0, stream>>>(qxb, WqT, bq, Qb, 0, 0.125f * L2E);
  gemm_bt<<<dim3(32, 8), 256, 0, stream>>>(vxb, WkT, bk, Kb, 0, 1.0f);
  gemm_bt<<<dim3(32, 8), 256, 0, stream>>>(vxb, WvT, bv, Vb, 0, 1.0f);
  vtrans<<<dim3(32, 32), 256, 0, stream>>>(Vb, VTb);
  flash<<<dim3(32, 32), 256, 0, stream>>>(Qb, Kb, VTb, amask, flg, ctx);
  gemm_bt<<<dim3(32, 8), 256, 0, stream>>>(ctx, WoT, bo, d_out, 1, 1.0f);
}

// Round 3
// 172.786 us; speedup vs baseline: 1.5641x; 1.2273x over previous
//
#include <hip/hip_runtime.h>
#include <hip/hip_bf16.h>
#include <stdint.h>

#define TSEQ 2048
#define DMODEL 1024
#define NHEAD 16
#define HDIM 64
#define MROWS 4096
#define L2E 1.44269504088896340736f

typedef unsigned short u16;
typedef __attribute__((ext_vector_type(8))) short bf16x8;
typedef __attribute__((ext_vector_type(8))) unsigned short u16x8;
typedef __attribute__((ext_vector_type(4))) unsigned short u16x4;
typedef __attribute__((ext_vector_type(4))) float f32x4;

__device__ inline u16 f2bf(float f) {
  __hip_bfloat16 h(f);
  return __builtin_bit_cast(u16, h);
}

#if defined(__has_builtin) && __has_builtin(__builtin_amdgcn_exp2f)
__device__ inline float fexp2(float x) { return __builtin_amdgcn_exp2f(x); }
#else
__device__ inline float fexp2(float x) { float r; asm("v_exp_f32 %0, %1" : "=v"(r) : "v"(x)); return r; }
#endif

__device__ inline unsigned cvtpk_bf16(float a, float b) {
  unsigned r; asm("v_cvt_pk_bf16_f32 %0, %1, %2" : "=v"(r) : "v"(a), "v"(b)); return r;
}

__device__ inline void gload16(const void* g, void* l) {
  __builtin_amdgcn_global_load_lds((const __attribute__((address_space(1))) void*)g,
                                   (__attribute__((address_space(3))) void*)l, 16, 0, 0);
}

// ---------------- f32 -> bf16, both activations in one dispatch ----------------
__global__ void cvt2(const float* __restrict__ q, const float* __restrict__ v,
                     u16* __restrict__ qo, u16* __restrict__ vo) {
  const float* in = blockIdx.y ? v : q;
  u16* out = blockIdx.y ? vo : qo;
  int i = (blockIdx.x * blockDim.x + threadIdx.x) * 4;
  float4 x = *(const float4*)(in + i);
  u16x4 o;
  o.x = f2bf(x.x); o.y = f2bf(x.y); o.z = f2bf(x.z); o.w = f2bf(x.w);
  *(u16x4*)(out + i) = o;
}

// ---------------- all 4 weight transposes in one dispatch ----------------
// z=0..2 -> WT3 (concat [3072][1024]); z=3 -> WoT
__global__ void wtrans4(const float* __restrict__ Wq, const float* __restrict__ Wk,
                        const float* __restrict__ Wv, const float* __restrict__ Wo,
                        u16* __restrict__ WT3, u16* __restrict__ WoT) {
  __shared__ float tile[32][33];
  const int z = blockIdx.z;
  const float* W = z == 0 ? Wq : z == 1 ? Wk : z == 2 ? Wv : Wo;
  u16* WT = z < 3 ? (WT3 + (size_t)z * 1024 * 1024) : WoT;
  const int bx = blockIdx.x, by = blockIdx.y;
  const int tr = threadIdx.x >> 3;
  const int tc4 = (threadIdx.x & 7) * 4;
  float4 v = *(const float4*)(W + (size_t)(by * 32 + tr) * 1024 + bx * 32 + tc4);
  tile[tr][tc4 + 0] = v.x; tile[tr][tc4 + 1] = v.y;
  tile[tr][tc4 + 2] = v.z; tile[tr][tc4 + 3] = v.w;
  __syncthreads();
  u16x4 o;
  o.x = f2bf(tile[tc4 + 0][tr]); o.y = f2bf(tile[tc4 + 1][tr]);
  o.z = f2bf(tile[tc4 + 2][tr]); o.w = f2bf(tile[tc4 + 3][tr]);
  *(u16x4*)(WT + (size_t)(bx * 32 + tr) * 1024 + by * 32 + tc4) = o;
}

// ---------------- mask tile flags: 1 if 128x128 tile is all ones ----------------
__global__ void maskflag(const int* __restrict__ mask, int* __restrict__ flags) {
  const int st = blockIdx.x, qt = blockIdx.y, b = blockIdx.z;
  const int row = qt * 128 + (threadIdx.x >> 1);
  const int col0 = st * 128 + (threadIdx.x & 1) * 64;
  const int* p = mask + (size_t)b * TSEQ * TSEQ + (size_t)row * TSEQ + col0;
  int ok = 1;
  #pragma unroll
  for (int j = 0; j < 64; j += 4) {
    int4 v = *(const int4*)(p + j);
    ok &= (v.x == 1) & (v.y == 1) & (v.z == 1) & (v.w == 1);
  }
  ok = __all(ok);
  __shared__ int s[4];
  if ((threadIdx.x & 63) == 0) s[threadIdx.x >> 6] = ok;
  __syncthreads();
  if (threadIdx.x == 0) flags[(b * 16 + qt) * 16 + st] = s[0] & s[1] & s[2] & s[3];
}

// ---------------- V[bh][t][64] -> VT[bh][64][t] (bf16) ----------------
__global__ void vtrans(const u16* __restrict__ V, u16* __restrict__ VT) {
  __shared__ u16 tile[64][72];
  const int bh = blockIdx.y;
  const int t0 = blockIdx.x * 64;
  const u16* src = V + ((size_t)bh * TSEQ + t0) * 64;
  const int r = threadIdx.x >> 3, sg = threadIdx.x & 7;
  #pragma unroll
  for (int i = 0; i < 2; ++i) {
    int row = r + i * 32;
    u16x8 v = *(const u16x8*)(src + (size_t)row * 64 + sg * 8);
    #pragma unroll
    for (int j = 0; j < 8; ++j) tile[row][sg * 8 + j] = v[j];
  }
  __syncthreads();
  u16* dst = VT + (size_t)bh * 64 * TSEQ;
  #pragma unroll
  for (int i = 0; i < 2; ++i) {
    int v = r + i * 32;
    u16x8 o;
    #pragma unroll
    for (int j = 0; j < 8; ++j) o[j] = tile[sg * 8 + j][v];
    *(u16x8*)(dst + (size_t)v * TSEQ + t0 + sg * 8) = o;
  }
}

// ---------------- fused QKV GEMM: [4096x1024] x WT3^T[3072x1024] ----------------
// n-block selects {Q,K,V}; A = qxb for Q, vxb for K/V; bf16 scatter to [B,H,T,64]
__global__ __launch_bounds__(256) void gemm_qkv(
    const u16* __restrict__ qxb, const u16* __restrict__ vxb, const u16* __restrict__ WT3,
    const float* __restrict__ bq, const float* __restrict__ bk, const float* __restrict__ bv,
    u16* __restrict__ Qb, u16* __restrict__ Kb, u16* __restrict__ Vb, float qscale) {
  __shared__ u16 As[128 * 64];
  __shared__ u16 Bs[128 * 64];
  const int tid = threadIdx.x;
  const int w = tid >> 6, lane = tid & 63;
  const int lo = lane & 15, hi = lane >> 4;
  const int m0 = blockIdx.x * 128, n0 = blockIdx.y * 128;
  const int nsel = n0 >> 10;
  const u16* A = nsel == 0 ? qxb : vxb;
  const float* bias = nsel == 0 ? bq : nsel == 1 ? bk : bv;
  u16* dst = nsel == 0 ? Qb : nsel == 1 ? Kb : Vb;
  const float scl = nsel == 0 ? qscale : 1.0f;
  const int wm = (w >> 1) * 64, wn = (w & 1) * 64;
  f32x4 acc[4][4] = {};
  const int loff = w * 4096 + lane * 16;
  for (int kt = 0; kt < 16; ++kt) {
    #pragma unroll
    for (int i = 0; i < 4; ++i) {
      const int off = loff + i * 1024;
      const int row = off >> 7;
      const int g = ((off >> 4) & 7) ^ (row & 7);
      gload16(A + (size_t)(m0 + row) * 1024 + kt * 64 + g * 8, (char*)As + off);
      gload16(WT3 + (size_t)(n0 + row) * 1024 + kt * 64 + g * 8, (char*)Bs + off);
    }
    __syncthreads();
    #pragma unroll
    for (int kk = 0; kk < 2; ++kk) {
      bf16x8 af[4], bfr[4];
      #pragma unroll
      for (int mi = 0; mi < 4; ++mi) {
        int row = wm + mi * 16 + lo;
        af[mi] = *(const bf16x8*)(As + row * 64 + (((kk * 4 + hi) ^ (row & 7)) << 3));
      }
      #pragma unroll
      for (int ni = 0; ni < 4; ++ni) {
        int row = wn + ni * 16 + lo;
        bfr[ni] = *(const bf16x8*)(Bs + row * 64 + (((kk * 4 + hi) ^ (row & 7)) << 3));
      }
      #pragma unroll
      for (int mi = 0; mi < 4; ++mi)
        #pragma unroll
        for (int ni = 0; ni < 4; ++ni)
          acc[mi][ni] = __builtin_amdgcn_mfma_f32_16x16x32_bf16(af[mi], bfr[ni], acc[mi][ni], 0, 0, 0);
    }
    __syncthreads();
  }
  #pragma unroll
  for (int ni = 0; ni < 4; ++ni) {
    const int col = (n0 + wn + ni * 16 + lo) & 1023;
    const float bc = bias[col];
    #pragma unroll
    for (int mi = 0; mi < 4; ++mi) {
      #pragma unroll
      for (int r = 0; r < 4; ++r) {
        const int row = m0 + wm + mi * 16 + hi * 4 + r;
        const float v = (acc[mi][ni][r] + bc) * scl;
        dst[(size_t)(((row >> 11) * NHEAD + (col >> 6)) * TSEQ + (row & 2047)) * HDIM + (col & 63)] = f2bf(v);
      }
    }
  }
}

// ---------------- output GEMM: ctx[4096x1024] x WoT^T -> f32 out ----------------
// BM=64, BN=128 -> grid 64x8 = 512 blocks (2/CU)
__global__ __launch_bounds__(256) void gemm_o(const u16* __restrict__ A, const u16* __restrict__ BT,
                                              const float* __restrict__ bias, float* __restrict__ C) {
  __shared__ u16 As[64 * 64];
  __shared__ u16 Bs[128 * 64];
  const int tid = threadIdx.x;
  const int w = tid >> 6, lane = tid & 63;
  const int lo = lane & 15, hi = lane >> 4;
  const int m0 = blockIdx.x * 64, n0 = blockIdx.y * 128;
  const int wm = (w >> 1) * 32, wn = (w & 1) * 64;
  f32x4 acc[2][4] = {};
  for (int kt = 0; kt < 16; ++kt) {
    #pragma unroll
    for (int i = 0; i < 2; ++i) {
      const int off = tid * 16 + i * 4096;
      const int row = off >> 7;
      const int g = ((off >> 4) & 7) ^ (row & 7);
      gload16(A + (size_t)(m0 + row) * 1024 + kt * 64 + g * 8, (char*)As + off);
    }
    #pragma unroll
    for (int i = 0; i < 4; ++i) {
      const int off = tid * 16 + i * 4096;
      const int row = off >> 7;
      const int g = ((off >> 4) & 7) ^ (row & 7);
      gload16(BT + (size_t)(n0 + row) * 1024 + kt * 64 + g * 8, (char*)Bs + off);
    }
    __syncthreads();
    #pragma unroll
    for (int kk = 0; kk < 2; ++kk) {
      bf16x8 af[2], bfr[4];
      #pragma unroll
      for (int mi = 0; mi < 2; ++mi) {
        int row = wm + mi * 16 + lo;
        af[mi] = *(const bf16x8*)(As + row * 64 + (((kk * 4 + hi) ^ (row & 7)) << 3));
      }
      #pragma unroll
      for (int ni = 0; ni < 4; ++ni) {
        int row = wn + ni * 16 + lo;
        bfr[ni] = *(const bf16x8*)(Bs + row * 64 + (((kk * 4 + hi) ^ (row & 7)) << 3));
      }
      #pragma unroll
      for (int mi = 0; mi < 2; ++mi)
        #pragma unroll
        for (int ni = 0; ni < 4; ++ni)
          acc[mi][ni] = __builtin_amdgcn_mfma_f32_16x16x32_bf16(af[mi], bfr[ni], acc[mi][ni], 0, 0, 0);
    }
    __syncthreads();
  }
  #pragma unroll
  for (int ni = 0; ni < 4; ++ni) {
    const int col = n0 + wn + ni * 16 + lo;
    const float bc = bias[col];
    #pragma unroll
    for (int mi = 0; mi < 2; ++mi)
      #pragma unroll
      for (int r = 0; r < 4; ++r) {
        const int row = m0 + wm + mi * 16 + hi * 4 + r;
        C[(size_t)row * DMODEL + col] = acc[mi][ni][r] + bc;
      }
  }
}

// ---------------- flash attention (swapped-QK, defer-max, 2-phase dbuf) ----------------
__global__ __launch_bounds__(256) void flash(
    const u16* __restrict__ Q, const u16* __restrict__ K, const u16* __restrict__ VT,
    const int* __restrict__ mask, const int* __restrict__ flags, u16* __restrict__ ctx) {
  __shared__ u16 Ks[2][64 * 64];
  __shared__ u16 Vs[2][64 * 64];
  __shared__ u16 Ps[4][16 * 64];
  const int tid = threadIdx.x, w = tid >> 6, lane = tid & 63;
  const int lo = lane & 15, hi = lane >> 4;
  const int qt = blockIdx.x, bh = blockIdx.y;
  const int b = bh >> 4, h = bh & 15;
  const int q0 = qt * 64;
  u16* Pw = &Ps[w][0];

  const int soff = w * 2048 + lane * 16;
  const int srow0 = w * 16 + (lane >> 3);
  const int g8 = (((lane & 7) ^ (lane >> 3)) << 3);

  bf16x8 qf[2];
  #pragma unroll
  for (int kk = 0; kk < 2; ++kk)
    qf[kk] = *(const bf16x8*)(Q + ((size_t)bh * TSEQ + q0 + w * 16 + lo) * 64 + kk * 32 + hi * 8);

  // preload all mask-tile flags for this q-block into a bitmask
  unsigned fl = 0;
  {
    const int* fp = flags + (b * 16 + (qt >> 1)) * 16;
    #pragma unroll
    for (int i = 0; i < 4; ++i) {
      int4 v = *(const int4*)(fp + i * 4);
      fl |= (unsigned)((v.x & 1) | ((v.y & 1) << 1) | ((v.z & 1) << 2) | ((v.w & 1) << 3)) << (4 * i);
    }
  }

  f32x4 o[4] = {};
  float mrow = -1e30f, lrow = 0.f;

#define STAGE(buf, st_) do {                                                         \
    const u16* kb_ = K + ((size_t)bh * TSEQ + (st_) * 64) * 64;                      \
    const u16* vb_ = VT + (size_t)bh * 64 * TSEQ + (st_) * 64;                       \
    gload16(kb_ + (size_t)srow0 * 64 + g8, (char*)Ks[buf] + soff);                   \
    gload16(kb_ + (size_t)(srow0 + 8) * 64 + g8, (char*)Ks[buf] + soff + 1024);      \
    gload16(vb_ + (size_t)srow0 * TSEQ + g8, (char*)Vs[buf] + soff);                 \
    gload16(vb_ + (size_t)(srow0 + 8) * TSEQ + g8, (char*)Vs[buf] + soff + 1024);    \
  } while (0)

  int cur = 0;
  STAGE(0, 0);
  __syncthreads();

  for (int st = 0; st < 32; ++st) {
    if (st < 31) STAGE(cur ^ 1, st + 1);
    const u16* Ksb = Ks[cur];
    const u16* Vsb = Vs[cur];

    f32x4 sc[4] = {};
    __builtin_amdgcn_s_setprio(1);
    #pragma unroll
    for (int kk = 0; kk < 2; ++kk) {
      const int p = ((kk * 4 + hi) ^ (lo & 7)) << 3;
      #pragma unroll
      for (int si = 0; si < 4; ++si) {
        bf16x8 kf = *(const bf16x8*)(Ksb + (si * 16 + lo) * 64 + p);
        sc[si] = __builtin_amdgcn_mfma_f32_16x16x32_bf16(kf, qf[kk], sc[si], 0, 0, 0);
      }
    }
    __builtin_amdgcn_s_setprio(0);

    if (!((fl >> (st >> 1)) & 1)) {
      const int t = q0 + w * 16 + lo;
      #pragma unroll
      for (int si = 0; si < 4; ++si)
        #pragma unroll
        for (int r = 0; r < 4; ++r) {
          int s = st * 64 + si * 16 + hi * 4 + r;
          int mv = mask[(size_t)b * TSEQ * TSEQ + (size_t)t * TSEQ + s];
          sc[si][r] += (1.0f - (float)mv) * -14426.950408f;  // -10000 * log2(e)
        }
    }

    float pm = sc[0][0];
    #pragma unroll
    for (int si = 0; si < 4; ++si)
      #pragma unroll
      for (int r = 0; r < 4; ++r) pm = fmaxf(pm, sc[si][r]);
    pm = fmaxf(pm, __shfl_xor(pm, 16));
    pm = fmaxf(pm, __shfl_xor(pm, 32));

    if (__any(pm - mrow > 11.0f)) {
      float mn = fmaxf(mrow, pm);
      float a = fexp2(mrow - mn);
      lrow *= a;
      mrow = mn;
      #pragma unroll
      for (int r = 0; r < 4; ++r) {
        float ar = __shfl(a, hi * 4 + r);
        #pragma unroll
        for (int vj = 0; vj < 4; ++vj) o[vj][r] *= ar;
      }
    }

    float rs = 0.f;
    #pragma unroll
    for (int si = 0; si < 4; ++si) {
      float p0 = fexp2(sc[si][0] - mrow);
      float p1 = fexp2(sc[si][1] - mrow);
      float p2 = fexp2(sc[si][2] - mrow);
      float p3 = fexp2(sc[si][3] - mrow);
      rs += (p0 + p1) + (p2 + p3);
      unsigned w0 = cvtpk_bf16(p0, p1);
      unsigned w1 = cvtpk_bf16(p2, p3);
      const int seg = si * 2 + (hi >> 1);
      *(uint2*)((char*)Pw + lo * 128 + ((seg ^ (lo & 7)) << 4) + ((hi & 1) << 3)) = make_uint2(w0, w1);
    }
    rs += __shfl_xor(rs, 16);
    rs += __shfl_xor(rs, 32);
    lrow += rs;

    __builtin_amdgcn_s_setprio(1);
    #pragma unroll
    for (int kk = 0; kk < 2; ++kk) {
      const int p = ((kk * 4 + hi) ^ (lo & 7)) << 3;
      bf16x8 pa = *(const bf16x8*)(Pw + lo * 64 + p);
      #pragma unroll
      for (int vj = 0; vj < 4; ++vj) {
        bf16x8 vf = *(const bf16x8*)(Vsb + (vj * 16 + lo) * 64 + p);
        o[vj] = __builtin_amdgcn_mfma_f32_16x16x32_bf16(pa, vf, o[vj], 0, 0, 0);
      }
    }
    __builtin_amdgcn_s_setprio(0);

    __syncthreads();
    cur ^= 1;
  }
#undef STAGE

  const float inv = 1.0f / lrow;
  #pragma unroll
  for (int r = 0; r < 4; ++r) {
    const float ir = __shfl(inv, hi * 4 + r);
    const int t = q0 + w * 16 + hi * 4 + r;
    #pragma unroll
    for (int vj = 0; vj < 4; ++vj) {
      const int col = h * 64 + vj * 16 + lo;
      ctx[(size_t)(b * TSEQ + t) * DMODEL + col] = f2bf(o[vj][r] * ir);
    }
  }
}

extern "C" void kernel_launch(void* const* d_in, const int* in_sizes, int n_in,
                              void* d_out, int out_size, void* d_ws, size_t ws_size,
                              hipStream_t stream) {
  (void)in_sizes; (void)n_in; (void)out_size; (void)ws_size;
  const float* query = (const float*)d_in[0];
  const float* value = (const float*)d_in[1];
  const float* Wq = (const float*)d_in[2];
  const float* bq = (const float*)d_in[3];
  const float* Wk = (const float*)d_in[4];
  const float* bk = (const float*)d_in[5];
  const float* Wv = (const float*)d_in[6];
  const float* bv = (const float*)d_in[7];
  const float* Wo = (const float*)d_in[8];
  const float* bo = (const float*)d_in[9];
  const int* amask = (const int*)d_in[10];

  char* ws = (char*)d_ws;
  const size_t MB = 1 << 20;
  u16* qxb = (u16*)(ws + 0 * MB);
  u16* vxb = (u16*)(ws + 8 * MB);
  u16* WT3 = (u16*)(ws + 16 * MB);   // 6 MB: Wq^T | Wk^T | Wv^T
  u16* WoT = (u16*)(ws + 22 * MB);
  u16* Qb  = (u16*)(ws + 24 * MB);
  u16* Kb  = (u16*)(ws + 32 * MB);
  u16* Vb  = (u16*)(ws + 40 * MB);
  u16* VTb = (u16*)(ws + 48 * MB);
  u16* ctx = (u16*)(ws + 56 * MB);
  int* flg = (int*)(ws + 64 * MB);

  cvt2<<<dim3(4096, 2), 256, 0, stream>>>(query, value, qxb, vxb);
  wtrans4<<<dim3(32, 32, 4), 256, 0, stream>>>(Wq, Wk, Wv, Wo, WT3, WoT);
  maskflag<<<dim3(16, 16, 2), 256, 0, stream>>>(amask, flg);

  // Q pre-scaled by 0.125 * log2(e) so attention scores are in log2 units.
  gemm_qkv<<<dim3(32, 24), 256, 0, stream>>>(qxb, vxb, WT3, bq, bk, bv, Qb, Kb, Vb, 0.125f * L2E);
  vtrans<<<dim3(32, 32), 256, 0, stream>>>(Vb, VTb);
  flash<<<dim3(32, 32), 256, 0, stream>>>(Qb, Kb, VTb, amask, flg, ctx);
  gemm_o<<<dim3(64, 8), 256, 0, stream>>>(ctx, WoT, bo, (float*)d_out);
}

// Round 4
// 152.717 us; speedup vs baseline: 1.7697x; 1.1314x over previous
//
#include <hip/hip_runtime.h>
#include <hip/hip_bf16.h>
#include <stdint.h>

#define TSEQ 2048
#define DMODEL 1024
#define NHEAD 16
#define HDIM 64
#define MROWS 4096
#define L2E 1.44269504088896340736f

typedef unsigned short u16;
typedef __attribute__((ext_vector_type(8))) short bf16x8;
typedef __attribute__((ext_vector_type(8))) unsigned short u16x8;
typedef __attribute__((ext_vector_type(4))) unsigned short u16x4;
typedef __attribute__((ext_vector_type(4))) float f32x4;

__device__ inline u16 f2bf(float f) {
  __hip_bfloat16 h(f);
  return __builtin_bit_cast(u16, h);
}

__device__ inline float fexp2(float x) { float r; asm("v_exp_f32 %0, %1" : "=v"(r) : "v"(x)); return r; }

__device__ inline unsigned cvtpk_bf16(float a, float b) {
  unsigned r; asm("v_cvt_pk_bf16_f32 %0, %1, %2" : "=v"(r) : "v"(a), "v"(b)); return r;
}

__device__ inline void gload16(const void* g, void* l) {
  __builtin_amdgcn_global_load_lds((const __attribute__((address_space(1))) void*)g,
                                   (__attribute__((address_space(3))) void*)l, 16, 0, 0);
}

// ---------------- f32 -> bf16, both activations in one dispatch ----------------
__global__ void cvt2(const float* __restrict__ q, const float* __restrict__ v,
                     u16* __restrict__ qo, u16* __restrict__ vo) {
  const float* in = blockIdx.y ? v : q;
  u16* out = blockIdx.y ? vo : qo;
  int i = (blockIdx.x * blockDim.x + threadIdx.x) * 4;
  float4 x = *(const float4*)(in + i);
  u16x4 o;
  o.x = f2bf(x.x); o.y = f2bf(x.y); o.z = f2bf(x.z); o.w = f2bf(x.w);
  *(u16x4*)(out + i) = o;
}

// ---------------- all 4 weight transposes in one dispatch ----------------
__global__ void wtrans4(const float* __restrict__ Wq, const float* __restrict__ Wk,
                        const float* __restrict__ Wv, const float* __restrict__ Wo,
                        u16* __restrict__ WT3, u16* __restrict__ WoT) {
  __shared__ float tile[32][33];
  const int z = blockIdx.z;
  const float* W = z == 0 ? Wq : z == 1 ? Wk : z == 2 ? Wv : Wo;
  u16* WT = z < 3 ? (WT3 + (size_t)z * 1024 * 1024) : WoT;
  const int bx = blockIdx.x, by = blockIdx.y;
  const int tr = threadIdx.x >> 3;
  const int tc4 = (threadIdx.x & 7) * 4;
  float4 v = *(const float4*)(W + (size_t)(by * 32 + tr) * 1024 + bx * 32 + tc4);
  tile[tr][tc4 + 0] = v.x; tile[tr][tc4 + 1] = v.y;
  tile[tr][tc4 + 2] = v.z; tile[tr][tc4 + 3] = v.w;
  __syncthreads();
  u16x4 o;
  o.x = f2bf(tile[tc4 + 0][tr]); o.y = f2bf(tile[tc4 + 1][tr]);
  o.z = f2bf(tile[tc4 + 2][tr]); o.w = f2bf(tile[tc4 + 3][tr]);
  *(u16x4*)(WT + (size_t)(bx * 32 + tr) * 1024 + by * 32 + tc4) = o;
}

// ---------------- mask tile flags: 1 if 128x128 tile is all ones ----------------
__global__ void maskflag(const int* __restrict__ mask, int* __restrict__ flags) {
  const int st = blockIdx.x, qt = blockIdx.y, b = blockIdx.z;
  const int row = qt * 128 + (threadIdx.x >> 1);
  const int col0 = st * 128 + (threadIdx.x & 1) * 64;
  const int* p = mask + (size_t)b * TSEQ * TSEQ + (size_t)row * TSEQ + col0;
  int ok = 1;
  #pragma unroll
  for (int j = 0; j < 64; j += 4) {
    int4 v = *(const int4*)(p + j);
    ok &= (v.x == 1) & (v.y == 1) & (v.z == 1) & (v.w == 1);
  }
  ok = __all(ok);
  __shared__ int s[4];
  if ((threadIdx.x & 63) == 0) s[threadIdx.x >> 6] = ok;
  __syncthreads();
  if (threadIdx.x == 0) flags[(b * 16 + qt) * 16 + st] = s[0] & s[1] & s[2] & s[3];
}

// ---------------- V[bh][t][64] -> VT[bh][64][t] (bf16) ----------------
__global__ void vtrans(const u16* __restrict__ V, u16* __restrict__ VT) {
  __shared__ u16 tile[64][72];
  const int bh = blockIdx.y;
  const int t0 = blockIdx.x * 64;
  const u16* src = V + ((size_t)bh * TSEQ + t0) * 64;
  const int r = threadIdx.x >> 3, sg = threadIdx.x & 7;
  #pragma unroll
  for (int i = 0; i < 2; ++i) {
    int row = r + i * 32;
    u16x8 v = *(const u16x8*)(src + (size_t)row * 64 + sg * 8);
    #pragma unroll
    for (int j = 0; j < 8; ++j) tile[row][sg * 8 + j] = v[j];
  }
  __syncthreads();
  u16* dst = VT + (size_t)bh * 64 * TSEQ;
  #pragma unroll
  for (int i = 0; i < 2; ++i) {
    int v = r + i * 32;
    u16x8 o;
    #pragma unroll
    for (int j = 0; j < 8; ++j) o[j] = tile[sg * 8 + j][v];
    *(u16x8*)(dst + (size_t)v * TSEQ + t0 + sg * 8) = o;
  }
}

// ---------------- fused QKV GEMM: [4096x1024] x WT3^T[3072x1024] ----------------
__global__ __launch_bounds__(256) void gemm_qkv(
    const u16* __restrict__ qxb, const u16* __restrict__ vxb, const u16* __restrict__ WT3,
    const float* __restrict__ bq, const float* __restrict__ bk, const float* __restrict__ bv,
    u16* __restrict__ Qb, u16* __restrict__ Kb, u16* __restrict__ Vb, float qscale) {
  __shared__ u16 As[128 * 64];
  __shared__ u16 Bs[128 * 64];
  const int tid = threadIdx.x;
  const int w = tid >> 6, lane = tid & 63;
  const int lo = lane & 15, hi = lane >> 4;
  const int m0 = blockIdx.x * 128, n0 = blockIdx.y * 128;
  const int nsel = n0 >> 10;
  const u16* A = nsel == 0 ? qxb : vxb;
  const float* bias = nsel == 0 ? bq : nsel == 1 ? bk : bv;
  u16* dst = nsel == 0 ? Qb : nsel == 1 ? Kb : Vb;
  const float scl = nsel == 0 ? qscale : 1.0f;
  const int wm = (w >> 1) * 64, wn = (w & 1) * 64;
  f32x4 acc[4][4] = {};
  const int loff = w * 4096 + lane * 16;
  for (int kt = 0; kt < 16; ++kt) {
    #pragma unroll
    for (int i = 0; i < 4; ++i) {
      const int off = loff + i * 1024;
      const int row = off >> 7;
      const int g = ((off >> 4) & 7) ^ (row & 7);
      gload16(A + (size_t)(m0 + row) * 1024 + kt * 64 + g * 8, (char*)As + off);
      gload16(WT3 + (size_t)(n0 + row) * 1024 + kt * 64 + g * 8, (char*)Bs + off);
    }
    __syncthreads();
    #pragma unroll
    for (int kk = 0; kk < 2; ++kk) {
      bf16x8 af[4], bfr[4];
      #pragma unroll
      for (int mi = 0; mi < 4; ++mi) {
        int row = wm + mi * 16 + lo;
        af[mi] = *(const bf16x8*)(As + row * 64 + (((kk * 4 + hi) ^ (row & 7)) << 3));
      }
      #pragma unroll
      for (int ni = 0; ni < 4; ++ni) {
        int row = wn + ni * 16 + lo;
        bfr[ni] = *(const bf16x8*)(Bs + row * 64 + (((kk * 4 + hi) ^ (row & 7)) << 3));
      }
      #pragma unroll
      for (int mi = 0; mi < 4; ++mi)
        #pragma unroll
        for (int ni = 0; ni < 4; ++ni)
          acc[mi][ni] = __builtin_amdgcn_mfma_f32_16x16x32_bf16(af[mi], bfr[ni], acc[mi][ni], 0, 0, 0);
    }
    __syncthreads();
  }
  #pragma unroll
  for (int ni = 0; ni < 4; ++ni) {
    const int col = (n0 + wn + ni * 16 + lo) & 1023;
    const float bc = bias[col];
    #pragma unroll
    for (int mi = 0; mi < 4; ++mi) {
      #pragma unroll
      for (int r = 0; r < 4; ++r) {
        const int row = m0 + wm + mi * 16 + hi * 4 + r;
        const float v = (acc[mi][ni][r] + bc) * scl;
        dst[(size_t)(((row >> 11) * NHEAD + (col >> 6)) * TSEQ + (row & 2047)) * HDIM + (col & 63)] = f2bf(v);
      }
    }
  }
}

// ---------------- output GEMM: ctx[4096x1024] x WoT^T -> f32 out ----------------
__global__ __launch_bounds__(256) void gemm_o(const u16* __restrict__ A, const u16* __restrict__ BT,
                                              const float* __restrict__ bias, float* __restrict__ C) {
  __shared__ u16 As[64 * 64];
  __shared__ u16 Bs[128 * 64];
  const int tid = threadIdx.x;
  const int w = tid >> 6, lane = tid & 63;
  const int lo = lane & 15, hi = lane >> 4;
  const int m0 = blockIdx.x * 64, n0 = blockIdx.y * 128;
  const int wm = (w >> 1) * 32, wn = (w & 1) * 64;
  f32x4 acc[2][4] = {};
  for (int kt = 0; kt < 16; ++kt) {
    #pragma unroll
    for (int i = 0; i < 2; ++i) {
      const int off = tid * 16 + i * 4096;
      const int row = off >> 7;
      const int g = ((off >> 4) & 7) ^ (row & 7);
      gload16(A + (size_t)(m0 + row) * 1024 + kt * 64 + g * 8, (char*)As + off);
    }
    #pragma unroll
    for (int i = 0; i < 4; ++i) {
      const int off = tid * 16 + i * 4096;
      const int row = off >> 7;
      const int g = ((off >> 4) & 7) ^ (row & 7);
      gload16(BT + (size_t)(n0 + row) * 1024 + kt * 64 + g * 8, (char*)Bs + off);
    }
    __syncthreads();
    #pragma unroll
    for (int kk = 0; kk < 2; ++kk) {
      bf16x8 af[2], bfr[4];
      #pragma unroll
      for (int mi = 0; mi < 2; ++mi) {
        int row = wm + mi * 16 + lo;
        af[mi] = *(const bf16x8*)(As + row * 64 + (((kk * 4 + hi) ^ (row & 7)) << 3));
      }
      #pragma unroll
      for (int ni = 0; ni < 4; ++ni) {
        int row = wn + ni * 16 + lo;
        bfr[ni] = *(const bf16x8*)(Bs + row * 64 + (((kk * 4 + hi) ^ (row & 7)) << 3));
      }
      #pragma unroll
      for (int mi = 0; mi < 2; ++mi)
        #pragma unroll
        for (int ni = 0; ni < 4; ++ni)
          acc[mi][ni] = __builtin_amdgcn_mfma_f32_16x16x32_bf16(af[mi], bfr[ni], acc[mi][ni], 0, 0, 0);
    }
    __syncthreads();
  }
  #pragma unroll
  for (int ni = 0; ni < 4; ++ni) {
    const int col = n0 + wn + ni * 16 + lo;
    const float bc = bias[col];
    #pragma unroll
    for (int mi = 0; mi < 2; ++mi)
      #pragma unroll
      for (int r = 0; r < 4; ++r) {
        const int row = m0 + wm + mi * 16 + hi * 4 + r;
        C[(size_t)row * DMODEL + col] = acc[mi][ni][r] + bc;
      }
  }
}

// ---------------- flash attention: 4 waves x 32 q-rows, KVBLK=64, dbuf ----------------
// Q pre-scaled by 0.125*log2(e). grid (16, 32): 128 q-rows per block.
__global__ __launch_bounds__(256) void flash(
    const u16* __restrict__ Q, const u16* __restrict__ K, const u16* __restrict__ VT,
    const int* __restrict__ mask, const int* __restrict__ flags, u16* __restrict__ ctx) {
  __shared__ u16 Ks[2][64 * 64];
  __shared__ u16 Vs[2][64 * 64];
  __shared__ u16 Ps[4][32 * 64];
  const int tid = threadIdx.x, w = tid >> 6, lane = tid & 63;
  const int lo = lane & 15, hi = lane >> 4;
  const int qt = blockIdx.x, bh = blockIdx.y;
  const int b = bh >> 4, h = bh & 15;
  const int q0 = qt * 128;
  u16* Pw = &Ps[w][0];

  const int soff = w * 2048 + lane * 16;
  const int srow0 = w * 16 + (lane >> 3);
  const int g8 = (((lane & 7) ^ (lane >> 3)) << 3);

  // Q fragments: t = q0 + w*32 + mi*16 + lo
  bf16x8 qf[2][2];
  #pragma unroll
  for (int mi = 0; mi < 2; ++mi)
    #pragma unroll
    for (int kk = 0; kk < 2; ++kk)
      qf[mi][kk] = *(const bf16x8*)(Q + ((size_t)bh * TSEQ + q0 + w * 32 + mi * 16 + lo) * 64 + kk * 32 + hi * 8);

  // preload mask-tile flags (q-block is exactly one 128-row flag tile)
  unsigned fl = 0;
  {
    const int* fp = flags + (b * 16 + qt) * 16;
    #pragma unroll
    for (int i = 0; i < 4; ++i) {
      int4 v = *(const int4*)(fp + i * 4);
      fl |= (unsigned)((v.x & 1) | ((v.y & 1) << 1) | ((v.z & 1) << 2) | ((v.w & 1) << 3)) << (4 * i);
    }
  }

  f32x4 o[2][4] = {};
  float mrow[2] = {-1e30f, -1e30f}, lrow[2] = {0.f, 0.f};

#define STAGE(buf, st_) do {                                                         \
    const u16* kb_ = K + ((size_t)bh * TSEQ + (st_) * 64) * 64;                      \
    const u16* vb_ = VT + (size_t)bh * 64 * TSEQ + (st_) * 64;                       \
    gload16(kb_ + (size_t)srow0 * 64 + g8, (char*)Ks[buf] + soff);                   \
    gload16(kb_ + (size_t)(srow0 + 8) * 64 + g8, (char*)Ks[buf] + soff + 1024);      \
    gload16(vb_ + (size_t)srow0 * TSEQ + g8, (char*)Vs[buf] + soff);                 \
    gload16(vb_ + (size_t)(srow0 + 8) * TSEQ + g8, (char*)Vs[buf] + soff + 1024);    \
  } while (0)

  int cur = 0;
  STAGE(0, 0);
  __syncthreads();

  for (int st = 0; st < 32; ++st) {
    if (st < 31) STAGE(cur ^ 1, st + 1);
    const u16* Ksb = Ks[cur];
    const u16* Vsb = Vs[cur];

    // S^T = K Q^T : sc[mi][si][r] = S[t = q0+w*32+mi*16+lo][s = st*64 + si*16 + hi*4 + r]
    f32x4 sc[2][4] = {};
    __builtin_amdgcn_s_setprio(1);
    #pragma unroll
    for (int kk = 0; kk < 2; ++kk) {
      const int p = ((kk * 4 + hi) ^ (lo & 7)) << 3;
      #pragma unroll
      for (int si = 0; si < 4; ++si) {
        bf16x8 kf = *(const bf16x8*)(Ksb + (si * 16 + lo) * 64 + p);
        #pragma unroll
        for (int mi = 0; mi < 2; ++mi)
          sc[mi][si] = __builtin_amdgcn_mfma_f32_16x16x32_bf16(kf, qf[mi][kk], sc[mi][si], 0, 0, 0);
      }
    }
    __builtin_amdgcn_s_setprio(0);

    if (!((fl >> (st >> 1)) & 1)) {
      #pragma unroll
      for (int mi = 0; mi < 2; ++mi) {
        const int t = q0 + w * 32 + mi * 16 + lo;
        #pragma unroll
        for (int si = 0; si < 4; ++si)
          #pragma unroll
          for (int r = 0; r < 4; ++r) {
            int s = st * 64 + si * 16 + hi * 4 + r;
            int mv = mask[(size_t)b * TSEQ * TSEQ + (size_t)t * TSEQ + s];
            sc[mi][si][r] += (1.0f - (float)mv) * -14426.950408f;  // -10000 * log2(e)
          }
      }
    }

    // row max per mi (lane-local 16 + 2 shfl)
    float pm[2];
    #pragma unroll
    for (int mi = 0; mi < 2; ++mi) {
      float m = sc[mi][0][0];
      #pragma unroll
      for (int si = 0; si < 4; ++si)
        #pragma unroll
        for (int r = 0; r < 4; ++r) m = fmaxf(m, sc[mi][si][r]);
      m = fmaxf(m, __shfl_xor(m, 16));
      m = fmaxf(m, __shfl_xor(m, 32));
      pm[mi] = m;
    }

    // defer-max rescale (rare)
    if (__any(fmaxf(pm[0] - mrow[0], pm[1] - mrow[1]) > 11.0f)) {
      #pragma unroll
      for (int mi = 0; mi < 2; ++mi) {
        float mn = fmaxf(mrow[mi], pm[mi]);
        float a = fexp2(mrow[mi] - mn);
        lrow[mi] *= a;
        mrow[mi] = mn;
        #pragma unroll
        for (int r = 0; r < 4; ++r) {
          float ar = __shfl(a, hi * 4 + r);
          #pragma unroll
          for (int vj = 0; vj < 4; ++vj) o[mi][vj][r] *= ar;
        }
      }
    }

    // P = exp2(S - m), row-sum, pack to wave-private LDS
    #pragma unroll
    for (int mi = 0; mi < 2; ++mi) {
      float rs = 0.f;
      const int tl = mi * 16 + lo;
      #pragma unroll
      for (int si = 0; si < 4; ++si) {
        float p0 = fexp2(sc[mi][si][0] - mrow[mi]);
        float p1 = fexp2(sc[mi][si][1] - mrow[mi]);
        float p2 = fexp2(sc[mi][si][2] - mrow[mi]);
        float p3 = fexp2(sc[mi][si][3] - mrow[mi]);
        rs += (p0 + p1) + (p2 + p3);
        unsigned w0 = cvtpk_bf16(p0, p1);
        unsigned w1 = cvtpk_bf16(p2, p3);
        const int seg = si * 2 + (hi >> 1);
        *(uint2*)((char*)Pw + tl * 128 + ((seg ^ (lo & 7)) << 4) + ((hi & 1) << 3)) = make_uint2(w0, w1);
      }
      rs += __shfl_xor(rs, 16);
      rs += __shfl_xor(rs, 32);
      lrow[mi] += rs;
    }

    // O += P V ; V fragments shared across mi
    __builtin_amdgcn_s_setprio(1);
    #pragma unroll
    for (int kk = 0; kk < 2; ++kk) {
      const int p = ((kk * 4 + hi) ^ (lo & 7)) << 3;
      bf16x8 pa[2];
      #pragma unroll
      for (int mi = 0; mi < 2; ++mi)
        pa[mi] = *(const bf16x8*)(Pw + (mi * 16 + lo) * 64 + p);
      #pragma unroll
      for (int vj = 0; vj < 4; ++vj) {
        bf16x8 vf = *(const bf16x8*)(Vsb + (vj * 16 + lo) * 64 + p);
        #pragma unroll
        for (int mi = 0; mi < 2; ++mi)
          o[mi][vj] = __builtin_amdgcn_mfma_f32_16x16x32_bf16(pa[mi], vf, o[mi][vj], 0, 0, 0);
      }
    }
    __builtin_amdgcn_s_setprio(0);

    __syncthreads();
    cur ^= 1;
  }
#undef STAGE

  // epilogue: normalize and store ctx
  #pragma unroll
  for (int mi = 0; mi < 2; ++mi) {
    const float inv = 1.0f / lrow[mi];
    #pragma unroll
    for (int r = 0; r < 4; ++r) {
      const float ir = __shfl(inv, hi * 4 + r);
      const int t = q0 + w * 32 + mi * 16 + hi * 4 + r;
      #pragma unroll
      for (int vj = 0; vj < 4; ++vj) {
        const int col = h * 64 + vj * 16 + lo;
        ctx[(size_t)(b * TSEQ + t) * DMODEL + col] = f2bf(o[mi][vj][r] * ir);
      }
    }
  }
}

extern "C" void kernel_launch(void* const* d_in, const int* in_sizes, int n_in,
                              void* d_out, int out_size, void* d_ws, size_t ws_size,
                              hipStream_t stream) {
  (void)in_sizes; (void)n_in; (void)out_size; (void)ws_size;
  const float* query = (const float*)d_in[0];
  const float* value = (const float*)d_in[1];
  const float* Wq = (const float*)d_in[2];
  const float* bq = (const float*)d_in[3];
  const float* Wk = (const float*)d_in[4];
  const float* bk = (const float*)d_in[5];
  const float* Wv = (const float*)d_in[6];
  const float* bv = (const float*)d_in[7];
  const float* Wo = (const float*)d_in[8];
  const float* bo = (const float*)d_in[9];
  const int* amask = (const int*)d_in[10];

  char* ws = (char*)d_ws;
  const size_t MB = 1 << 20;
  u16* qxb = (u16*)(ws + 0 * MB);
  u16* vxb = (u16*)(ws + 8 * MB);
  u16* WT3 = (u16*)(ws + 16 * MB);
  u16* WoT = (u16*)(ws + 22 * MB);
  u16* Qb  = (u16*)(ws + 24 * MB);
  u16* Kb  = (u16*)(ws + 32 * MB);
  u16* Vb  = (u16*)(ws + 40 * MB);
  u16* VTb = (u16*)(ws + 48 * MB);
  u16* ctx = (u16*)(ws + 56 * MB);
  int* flg = (int*)(ws + 64 * MB);

  cvt2<<<dim3(4096, 2), 256, 0, stream>>>(query, value, qxb, vxb);
  wtrans4<<<dim3(32, 32, 4), 256, 0, stream>>>(Wq, Wk, Wv, Wo, WT3, WoT);
  maskflag<<<dim3(16, 16, 2), 256, 0, stream>>>(amask, flg);

  gemm_qkv<<<dim3(32, 24), 256, 0, stream>>>(qxb, vxb, WT3, bq, bk, bv, Qb, Kb, Vb, 0.125f * L2E);
  vtrans<<<dim3(32, 32), 256, 0, stream>>>(Vb, VTb);
  flash<<<dim3(16, 32), 256, 0, stream>>>(Qb, Kb, VTb, amask, flg, ctx);
  gemm_o<<<dim3(64, 8), 256, 0, stream>>>(ctx, WoT, bo, (float*)d_out);
}